// Round 2
// baseline (1516.285 us; speedup 1.0000x reference)
//
#include <hip/hip_runtime.h>

#define NROWS 65536
#define KCODE 2048
#define DDIM  128

static constexpr float DECAYF = 0.99f;
static constexpr float OMDF   = (float)(1.0 - 0.99);     // f32(0.010000000000000009) == 0.01f
static constexpr float EPSF   = 1e-5f;
static constexpr float KEPSF  = (float)(2048.0 * 1e-5);  // f32(0.02048)

// ---------------- kernel 1: per-code sum of squares (XLA elemental order:
// strict sequential ascending, rounded squares, NO fma) ----------------
__global__ __launch_bounds__(256) void k_sumsq_emb(const float* __restrict__ emb,
                                                   float* __restrict__ se) {
#pragma clang fp contract(off)
  int k = blockIdx.x * 256 + threadIdx.x;
  if (k >= KCODE) return;
  const float* row = emb + (size_t)k * DDIM;
  float s = 0.f;
#pragma unroll
  for (int d = 0; d < DDIM; ++d) {
    float q = row[d] * row[d];  // rounded square (contract off)
    s = s + q;                  // sequential add
  }
  se[k] = s;
}

// ---------------- kernel 2: argmin over half the codebook ----------------
// sx: sequential rounded-square sum (XLA elemental reduce order)
// dot: sequential ascending-k FMA chain (Eigen/oneDNN sgemm order)
// d = fl(fl(sx+se[k]) - fl(2*dot)); strict < (first-occurrence argmin)
__global__ __launch_bounds__(256) void k_argmin(const float* __restrict__ x,
                                                const float* __restrict__ emb,
                                                const float* __restrict__ se,
                                                float* __restrict__ bestd_out,
                                                int* __restrict__ bestk_out) {
#pragma clang fp contract(off)
  int n = blockIdx.x * 256 + threadIdx.x;
  int kbase = blockIdx.y * (KCODE / 2);

  const float4* xp = (const float4*)(x + (size_t)n * DDIM);
  float4 xr[32];
#pragma unroll
  for (int j = 0; j < 32; ++j) xr[j] = xp[j];

  // sequential sum of rounded squares, ascending d
  float sx = 0.f;
#pragma unroll
  for (int j = 0; j < 32; ++j) {
    float q0 = xr[j].x * xr[j].x; sx = sx + q0;
    float q1 = xr[j].y * xr[j].y; sx = sx + q1;
    float q2 = xr[j].z * xr[j].z; sx = sx + q2;
    float q3 = xr[j].w * xr[j].w; sx = sx + q3;
  }

  float bestd = INFINITY;
  int bestk = kbase;
  for (int k0 = kbase; k0 < kbase + KCODE / 2; k0 += 8) {
    float c[8];
#pragma unroll
    for (int j = 0; j < 8; ++j) c[j] = 0.f;
    // 8 independent sequential-k FMA chains (ILP across j, strict order in d)
#pragma unroll
    for (int d4 = 0; d4 < 32; ++d4) {
#pragma unroll
      for (int j = 0; j < 8; ++j) {
        float4 e = ((const float4*)(emb + (size_t)(k0 + j) * DDIM))[d4];  // wave-uniform
        c[j] = fmaf(e.x, xr[d4].x, c[j]);
        c[j] = fmaf(e.y, xr[d4].y, c[j]);
        c[j] = fmaf(e.z, xr[d4].z, c[j]);
        c[j] = fmaf(e.w, xr[d4].w, c[j]);
      }
    }
#pragma unroll
    for (int j = 0; j < 8; ++j) {
      float t = sx + se[k0 + j];   // rounded add (broadcast add in ref)
      float tw = 2.0f * c[j];      // exact
      float d = t - tw;            // rounded sub
      if (d < bestd) { bestd = d; bestk = k0 + j; }
    }
  }
  size_t off = (size_t)blockIdx.y * NROWS + n;
  bestd_out[off] = bestd;
  bestk_out[off] = bestk;
}

// ---------------- kernel 3: combine the two K-halves ----------------
__global__ __launch_bounds__(256) void k_combine(const float* __restrict__ bd,
                                                 const int* __restrict__ bk,
                                                 int* __restrict__ idx,
                                                 float* __restrict__ idxf) {
  int n = blockIdx.x * 256 + threadIdx.x;
  float d0 = bd[n], d1 = bd[NROWS + n];
  int k0 = bk[n], k1 = bk[NROWS + n];
  int k = (d1 < d0) ? k1 : k0;  // tie -> lower half -> lower index (first occurrence)
  idx[n] = k;
  idxf[n] = (float)k;
}

// ------- kernel 4: gather/quantize + straight-through out + loss + EMA scatter -------
__global__ __launch_bounds__(256) void k_quant(const float* __restrict__ x,
                                               const float* __restrict__ emb,
                                               const int* __restrict__ idx,
                                               float* __restrict__ out_q,
                                               float* __restrict__ dw,
                                               float* __restrict__ dwe,
                                               double* __restrict__ loss_acc) {
#pragma clang fp contract(off)
  int t = blockIdx.x * 256 + threadIdx.x;  // [0, NROWS*32)
  int n = t >> 5, j = t & 31;
  int k = idx[n];
  float4 xv = ((const float4*)(x + (size_t)n * DDIM))[j];
  float4 ev = ((const float4*)(emb + (size_t)k * DDIM))[j];
  float d0 = ev.x - xv.x, d1 = ev.y - xv.y, d2 = ev.z - xv.z, d3 = ev.w - xv.w;
  float4 q;
  q.x = xv.x + d0; q.y = xv.y + d1; q.z = xv.z + d2; q.w = xv.w + d3;
  ((float4*)(out_q + (size_t)n * DDIM))[j] = q;

  float s = d0 * d0 + d1 * d1 + d2 * d2 + d3 * d3;
  __shared__ float red[256];
  red[threadIdx.x] = s;
  __syncthreads();
  for (int o = 128; o > 0; o >>= 1) {
    if (threadIdx.x < o) red[threadIdx.x] += red[threadIdx.x + o];
    __syncthreads();
  }
  if (threadIdx.x == 0) unsafeAtomicAdd(loss_acc, (double)red[0]);

  float* dst = dwe + (size_t)k * DDIM + 4 * j;
  unsafeAtomicAdd(dst + 0, xv.x);
  unsafeAtomicAdd(dst + 1, xv.y);
  unsafeAtomicAdd(dst + 2, xv.z);
  unsafeAtomicAdd(dst + 3, xv.w);
  if (j == 0) unsafeAtomicAdd(&dw[k], 1.0f);
}

// ---------------- kernel 5: cluster-size EMA, n-sum, smoothing, loss ----------------
__global__ __launch_bounds__(1024) void k_final1(const float* __restrict__ cs,
                                                 const float* __restrict__ dw,
                                                 float* __restrict__ out_ncs,
                                                 float* __restrict__ smoothed,
                                                 const double* __restrict__ loss_acc,
                                                 float* __restrict__ out_loss) {
#pragma clang fp contract(off)
  __shared__ float red[1024];
  int t = threadIdx.x;
  float p0 = cs[t] * DECAYF;
  float p1 = cs[t + 1024] * DECAYF;
  float w0 = OMDF * dw[t];
  float w1 = OMDF * dw[t + 1024];
  float ncs0 = p0 + w0;
  float ncs1 = p1 + w1;
  out_ncs[t] = ncs0;
  out_ncs[t + 1024] = ncs1;
  red[t] = ncs0 + ncs1;
  __syncthreads();
  for (int o = 512; o > 0; o >>= 1) {
    if (t < o) red[t] += red[t + o];
    __syncthreads();
  }
  float nsum = red[0];
  smoothed[t] = (ncs0 + EPSF) / (nsum + KEPSF) * nsum;
  smoothed[t + 1024] = (ncs1 + EPSF) / (nsum + KEPSF) * nsum;
  if (t == 0) {
    float m = (float)(loss_acc[0] / (double)((size_t)NROWS * DDIM));
    out_loss[0] = m + 1.0f * m;  // q_latent + 1.0*e_latent
  }
}

// ---------------- kernel 6: embed_avg EMA + new embedding ----------------
__global__ __launch_bounds__(256) void k_final2(const float* __restrict__ ea,
                                                const float* __restrict__ dwe,
                                                const float* __restrict__ smoothed,
                                                float* __restrict__ out_ne,
                                                float* __restrict__ out_nea) {
#pragma clang fp contract(off)
  int i = blockIdx.x * 256 + threadIdx.x;  // [0, KCODE*DDIM)
  float p = ea[i] * DECAYF;
  float w = OMDF * dwe[i];
  float nea = p + w;
  out_nea[i] = nea;
  out_ne[i] = nea / smoothed[i >> 7];
}

extern "C" void kernel_launch(void* const* d_in, const int* in_sizes, int n_in,
                              void* d_out, int out_size, void* d_ws, size_t ws_size,
                              hipStream_t stream) {
  const float* x   = (const float*)d_in[0];   // inputs [N,D]
  const float* emb = (const float*)d_in[1];   // embedding [K,D]
  const float* cs  = (const float*)d_in[2];   // cluster_size [K]
  const float* ea  = (const float*)d_in[3];   // embed_avg [K,D]

  float* out = (float*)d_out;
  float* out_q    = out;                    // [N*D]   = 8388608
  float* out_loss = out + 8388608;          // [1]
  float* out_idx  = out + 8388609;          // [N]     = 65536
  float* out_ne   = out + 8454145;          // [K*D]   = 262144
  float* out_ncs  = out + 8716289;          // [K]     = 2048
  float* out_nea  = out + 8718337;          // [K*D]   = 262144

  char* ws = (char*)d_ws;
  float*  bestd    = (float*)(ws + 0);        // 2*N floats   = 524288 B
  int*    bestk    = (int*)(ws + 524288);     // 2*N ints     = 524288 B
  int*    idx      = (int*)(ws + 1048576);    // N ints       = 262144 B
  float*  dwe      = (float*)(ws + 1310720);  // K*D floats   = 1048576 B
  float*  dw       = (float*)(ws + 2359296);  // K floats     = 8192 B
  float*  se       = (float*)(ws + 2367488);  // K floats     = 8192 B
  float*  smoothed = (float*)(ws + 2375680);  // K floats     = 8192 B
  double* loss_acc = (double*)(ws + 2383872); // 8 B

  // zero the accumulators (ws is poisoned before every launch)
  hipMemsetAsync(ws + 1310720, 0, 1048576 + 8192, stream);  // dwe + dw
  hipMemsetAsync(ws + 2383872, 0, 8, stream);               // loss_acc

  k_sumsq_emb<<<(KCODE + 255) / 256, 256, 0, stream>>>(emb, se);
  k_argmin<<<dim3(NROWS / 256, 2), 256, 0, stream>>>(x, emb, se, bestd, bestk);
  k_combine<<<NROWS / 256, 256, 0, stream>>>(bestd, bestk, idx, out_idx);
  k_quant<<<(NROWS * 32) / 256, 256, 0, stream>>>(x, emb, idx, out_q, dw, dwe, loss_acc);
  k_final1<<<1, 1024, 0, stream>>>(cs, dw, out_ncs, smoothed, loss_acc, out_loss);
  k_final2<<<(KCODE * DDIM) / 256, 256, 0, stream>>>(ea, dwe, smoothed, out_ne, out_nea);
}

// Round 5
// 634.408 us; speedup vs baseline: 2.3901x; 2.3901x over previous
//
#include <hip/hip_runtime.h>

#define NROWS 65536
#define KCODE 2048
#define DDIM  128

static constexpr float DECAYF = 0.99f;
static constexpr float OMDF   = (float)(1.0 - 0.99);
static constexpr float EPSF   = 1e-5f;
static constexpr float KEPSF  = (float)(2048.0 * 1e-5);
static constexpr float MARGIN = 1e-3f;

typedef __attribute__((ext_vector_type(8))) short bf16x8;
typedef __attribute__((ext_vector_type(4))) float f32x4;

__device__ __forceinline__ unsigned int bf16_rne_bits(float f) {
  unsigned int u = __builtin_bit_cast(unsigned int, f);
  return (u + 0x7fffu + ((u >> 16) & 1u)) >> 16;
}

// ---------------- kernel: split codebook into bf16 hi/lo planes ----------------
__global__ __launch_bounds__(256) void k_split(const float* __restrict__ emb,
                                               unsigned short* __restrict__ ehi,
                                               unsigned short* __restrict__ elo) {
  int i = blockIdx.x * 256 + threadIdx.x;
  float f = emb[i];
  unsigned int hr = bf16_rne_bits(f);
  float hif = __builtin_bit_cast(float, hr << 16);
  float lo = f - hif;                    // exact (Sterbenz)
  unsigned int lr = bf16_rne_bits(lo);
  ehi[i] = (unsigned short)hr;
  elo[i] = (unsigned short)lr;
}

// ---------------- kernel: per-code sum of squares (exact ref order) ----------------
__global__ __launch_bounds__(256) void k_sumsq_emb(const float* __restrict__ emb,
                                                   float* __restrict__ se) {
#pragma clang fp contract(off)
  int k = blockIdx.x * 256 + threadIdx.x;
  if (k >= KCODE) return;
  const float* row = emb + (size_t)k * DDIM;
  float s = 0.f;
#pragma unroll
  for (int d = 0; d < DDIM; ++d) {
    float q = row[d] * row[d];
    s = s + q;
  }
  se[k] = s;
}

// ---------------- kernel: MFMA screen (approx distances, min/argmin/2nd-min) ----------------
#define COMPUTE_GROUP(BH, BL, G)                                              \
  {                                                                           \
    int c_ = (G) * 16 + l15;                                                  \
    float sec_ = se[c_];                                                      \
    f32x4 a0 = {0.f, 0.f, 0.f, 0.f};                                          \
    f32x4 a1 = {0.f, 0.f, 0.f, 0.f};                                          \
    _Pragma("unroll")                                                         \
    for (int f = 0; f < 4; ++f) {                                             \
      a0 = __builtin_amdgcn_mfma_f32_16x16x32_bf16(ahi0[f], BH[f], a0, 0, 0, 0); \
      a0 = __builtin_amdgcn_mfma_f32_16x16x32_bf16(ahi0[f], BL[f], a0, 0, 0, 0); \
      a0 = __builtin_amdgcn_mfma_f32_16x16x32_bf16(alo0[f], BH[f], a0, 0, 0, 0); \
      a1 = __builtin_amdgcn_mfma_f32_16x16x32_bf16(ahi1[f], BH[f], a1, 0, 0, 0); \
      a1 = __builtin_amdgcn_mfma_f32_16x16x32_bf16(ahi1[f], BL[f], a1, 0, 0, 0); \
      a1 = __builtin_amdgcn_mfma_f32_16x16x32_bf16(alo1[f], BH[f], a1, 0, 0, 0); \
    }                                                                         \
    _Pragma("unroll")                                                         \
    for (int s = 0; s < 4; ++s) {                                             \
      float vv = fmaf(-2.f, a0[s], sec_);                                     \
      m2[s] = fminf(m2[s], fmaxf(vv, m1[s]));                                 \
      k1[s] = (vv < m1[s]) ? c_ : k1[s];                                      \
      m1[s] = fminf(m1[s], vv);                                               \
    }                                                                         \
    _Pragma("unroll")                                                         \
    for (int s = 0; s < 4; ++s) {                                             \
      float vv = fmaf(-2.f, a1[s], sec_);                                     \
      m2[s + 4] = fminf(m2[s + 4], fmaxf(vv, m1[s + 4]));                     \
      k1[s + 4] = (vv < m1[s + 4]) ? c_ : k1[s + 4];                          \
      m1[s + 4] = fminf(m1[s + 4], vv);                                       \
    }                                                                         \
  }

#define LOAD_B(BH, BL, G)                                                     \
  {                                                                           \
    _Pragma("unroll")                                                         \
    for (int f = 0; f < 4; ++f) {                                             \
      size_t o_ = (size_t)((G) * 16 + l15) * DDIM + f * 32 + l4 * 8;          \
      BH[f] = *(const bf16x8*)(ehi + o_);                                     \
      BL[f] = *(const bf16x8*)(elo + o_);                                     \
    }                                                                         \
  }

__global__ __launch_bounds__(256, 2) void k_screen(
    const float* __restrict__ x, const unsigned short* __restrict__ ehi,
    const unsigned short* __restrict__ elo, const float* __restrict__ se,
    float* __restrict__ out_idxf, int* __restrict__ idx,
    int* __restrict__ flaglist, int* __restrict__ flagcnt) {
  const int lane = threadIdx.x & 63;
  const int wid = threadIdx.x >> 6;
  const int rowbase = (blockIdx.x * 4 + wid) * 32;
  const int l15 = lane & 15, l4 = lane >> 4;

  // A fragments: 2 row-tiles x 4 k-frags, hi+lo (split on the fly)
  bf16x8 ahi0[4], alo0[4], ahi1[4], alo1[4];
#pragma unroll
  for (int t = 0; t < 2; ++t) {
#pragma unroll
    for (int f = 0; f < 4; ++f) {
      const float* src = x + (size_t)(rowbase + t * 16 + l15) * DDIM + f * 32 + l4 * 8;
      union { unsigned short u[8]; bf16x8 v; } H, L;
#pragma unroll
      for (int j = 0; j < 8; ++j) {
        float fj = src[j];
        unsigned int hr = bf16_rne_bits(fj);
        float hif = __builtin_bit_cast(float, hr << 16);
        unsigned int lr = bf16_rne_bits(fj - hif);
        H.u[j] = (unsigned short)hr;
        L.u[j] = (unsigned short)lr;
      }
      if (t == 0) { ahi0[f] = H.v; alo0[f] = L.v; }
      else        { ahi1[f] = H.v; alo1[f] = L.v; }
    }
  }

  float m1[8], m2[8];
  int k1[8];
#pragma unroll
  for (int s = 0; s < 8; ++s) { m1[s] = INFINITY; m2[s] = INFINITY; k1[s] = 0; }

  bf16x8 b0h[4], b0l[4], b1h[4], b1l[4];
  LOAD_B(b0h, b0l, 0)
  for (int g = 0; g < 128; g += 2) {
    LOAD_B(b1h, b1l, g + 1)
    COMPUTE_GROUP(b0h, b0l, g)
    int g2 = (g + 2 < 128) ? g + 2 : 127;
    LOAD_B(b0h, b0l, g2)
    COMPUTE_GROUP(b1h, b1l, g + 1)
  }

  // cross-lane combine over the 16 cols (low 4 lane bits)
#pragma unroll
  for (int off = 1; off < 16; off <<= 1) {
#pragma unroll
    for (int s = 0; s < 8; ++s) {
      float om1 = __shfl_xor(m1[s], off);
      float om2 = __shfl_xor(m2[s], off);
      int ok1 = __shfl_xor(k1[s], off);
      m2[s] = fminf(fminf(m2[s], om2), fmaxf(m1[s], om1));
      k1[s] = (om1 < m1[s]) ? ok1 : k1[s];
      m1[s] = fminf(m1[s], om1);
    }
  }
  if (l15 == 0) {
#pragma unroll
    for (int s = 0; s < 8; ++s) {
      int row = rowbase + (s >> 2) * 16 + l4 * 4 + (s & 3);
      idx[row] = k1[s];
      out_idxf[row] = (float)k1[s];
      if (m2[s] - m1[s] <= MARGIN) {
        int p = atomicAdd(flagcnt, 1);
        if (p < NROWS) flaglist[p] = row;
      }
    }
  }
}

// ---------------- kernel: exact re-rank of flagged rows (ref-identical arithmetic) ----------------
__global__ __launch_bounds__(64) void k_exact(
    const float* __restrict__ x, const float* __restrict__ emb,
    const float* __restrict__ se, const int* __restrict__ flaglist,
    const int* __restrict__ flagcnt, int* __restrict__ idx,
    float* __restrict__ out_idxf) {
#pragma clang fp contract(off)
  int cnt = *flagcnt;
  if (cnt > NROWS) cnt = NROWS;
  int lane = threadIdx.x;
  for (int i = blockIdx.x; i < cnt; i += gridDim.x) {
    int row = flaglist[i];
    const float4* xp = (const float4*)(x + (size_t)row * DDIM);
    float4 xr[32];
#pragma unroll
    for (int j = 0; j < 32; ++j) xr[j] = xp[j];
    float sx = 0.f;
#pragma unroll
    for (int j = 0; j < 32; ++j) {
      float q0 = xr[j].x * xr[j].x; sx = sx + q0;
      float q1 = xr[j].y * xr[j].y; sx = sx + q1;
      float q2 = xr[j].z * xr[j].z; sx = sx + q2;
      float q3 = xr[j].w * xr[j].w; sx = sx + q3;
    }
    float bestd = INFINITY;
    int bestk = lane * 32;
    for (int cb = 0; cb < 32; cb += 4) {
      float c4[4] = {0.f, 0.f, 0.f, 0.f};
#pragma unroll
      for (int d4 = 0; d4 < 32; ++d4) {
#pragma unroll
        for (int u = 0; u < 4; ++u) {
          float4 e = ((const float4*)(emb + (size_t)(lane * 32 + cb + u) * DDIM))[d4];
          c4[u] = fmaf(e.x, xr[d4].x, c4[u]);
          c4[u] = fmaf(e.y, xr[d4].y, c4[u]);
          c4[u] = fmaf(e.z, xr[d4].z, c4[u]);
          c4[u] = fmaf(e.w, xr[d4].w, c4[u]);
        }
      }
#pragma unroll
      for (int u = 0; u < 4; ++u) {
        int c = lane * 32 + cb + u;
        float t = sx + se[c];
        float tw = 2.0f * c4[u];
        float d = t - tw;
        if (d < bestd) { bestd = d; bestk = c; }
      }
    }
#pragma unroll
    for (int off = 1; off < 64; off <<= 1) {
      float od = __shfl_xor(bestd, off);
      int ok = __shfl_xor(bestk, off);
      if (od < bestd || (od == bestd && ok < bestk)) { bestd = od; bestk = ok; }
    }
    if (lane == 0) { idx[row] = bestk; out_idxf[row] = (float)bestk; }
  }
}

// ------- kernel: gather/quantize + ST output + loss + EMA scatter -------
__global__ __launch_bounds__(256) void k_quant(const float* __restrict__ x,
                                               const float* __restrict__ emb,
                                               const int* __restrict__ idx,
                                               float* __restrict__ out_q,
                                               float* __restrict__ dw,
                                               float* __restrict__ dwe,
                                               double* __restrict__ loss_acc) {
#pragma clang fp contract(off)
  int t = blockIdx.x * 256 + threadIdx.x;
  int n = t >> 5, j = t & 31;
  int k = idx[n];
  float4 xv = ((const float4*)(x + (size_t)n * DDIM))[j];
  float4 ev = ((const float4*)(emb + (size_t)k * DDIM))[j];
  float d0 = ev.x - xv.x, d1 = ev.y - xv.y, d2 = ev.z - xv.z, d3 = ev.w - xv.w;
  float4 q;
  q.x = xv.x + d0; q.y = xv.y + d1; q.z = xv.z + d2; q.w = xv.w + d3;
  ((float4*)(out_q + (size_t)n * DDIM))[j] = q;

  float s = d0 * d0 + d1 * d1 + d2 * d2 + d3 * d3;
  __shared__ float red[256];
  red[threadIdx.x] = s;
  __syncthreads();
  for (int o = 128; o > 0; o >>= 1) {
    if (threadIdx.x < o) red[threadIdx.x] += red[threadIdx.x + o];
    __syncthreads();
  }
  if (threadIdx.x == 0) unsafeAtomicAdd(loss_acc, (double)red[0]);

  float* dst = dwe + (size_t)k * DDIM + 4 * j;
  unsafeAtomicAdd(dst + 0, xv.x);
  unsafeAtomicAdd(dst + 1, xv.y);
  unsafeAtomicAdd(dst + 2, xv.z);
  unsafeAtomicAdd(dst + 3, xv.w);
  if (j == 0) unsafeAtomicAdd(&dw[k], 1.0f);
}

// ---------------- kernel: cluster-size EMA, n-sum, smoothing, loss ----------------
__global__ __launch_bounds__(1024) void k_final1(const float* __restrict__ cs,
                                                 const float* __restrict__ dw,
                                                 float* __restrict__ out_ncs,
                                                 float* __restrict__ smoothed,
                                                 const double* __restrict__ loss_acc,
                                                 float* __restrict__ out_loss) {
#pragma clang fp contract(off)
  __shared__ float red[1024];
  int t = threadIdx.x;
  float p0 = cs[t] * DECAYF;
  float p1 = cs[t + 1024] * DECAYF;
  float w0 = OMDF * dw[t];
  float w1 = OMDF * dw[t + 1024];
  float ncs0 = p0 + w0;
  float ncs1 = p1 + w1;
  out_ncs[t] = ncs0;
  out_ncs[t + 1024] = ncs1;
  red[t] = ncs0 + ncs1;
  __syncthreads();
  for (int o = 512; o > 0; o >>= 1) {
    if (t < o) red[t] += red[t + o];
    __syncthreads();
  }
  float nsum = red[0];
  smoothed[t] = (ncs0 + EPSF) / (nsum + KEPSF) * nsum;
  smoothed[t + 1024] = (ncs1 + EPSF) / (nsum + KEPSF) * nsum;
  if (t == 0) {
    float m = (float)(loss_acc[0] / (double)((size_t)NROWS * DDIM));
    out_loss[0] = m + 1.0f * m;
  }
}

// ---------------- kernel: embed_avg EMA + new embedding ----------------
__global__ __launch_bounds__(256) void k_final2(const float* __restrict__ ea,
                                                const float* __restrict__ dwe,
                                                const float* __restrict__ smoothed,
                                                float* __restrict__ out_ne,
                                                float* __restrict__ out_nea) {
#pragma clang fp contract(off)
  int i = blockIdx.x * 256 + threadIdx.x;
  float p = ea[i] * DECAYF;
  float w = OMDF * dwe[i];
  float nea = p + w;
  out_nea[i] = nea;
  out_ne[i] = nea / smoothed[i >> 7];
}

extern "C" void kernel_launch(void* const* d_in, const int* in_sizes, int n_in,
                              void* d_out, int out_size, void* d_ws, size_t ws_size,
                              hipStream_t stream) {
  const float* x   = (const float*)d_in[0];
  const float* emb = (const float*)d_in[1];
  const float* cs  = (const float*)d_in[2];
  const float* ea  = (const float*)d_in[3];

  float* out = (float*)d_out;
  float* out_q    = out;            // [N*D]
  float* out_loss = out + 8388608;  // [1]
  float* out_idx  = out + 8388609;  // [N] (float-encoded ints)
  float* out_ne   = out + 8454145;  // [K*D]
  float* out_ncs  = out + 8716289;  // [K]
  float* out_nea  = out + 8718337;  // [K*D]

  char* ws = (char*)d_ws;
  unsigned short* ehi = (unsigned short*)(ws + 0);        // 512 KB
  unsigned short* elo = (unsigned short*)(ws + 524288);   // 512 KB
  int*    idx      = (int*)(ws + 1048576);                // 256 KB
  int*    flaglist = (int*)(ws + 1310720);                // 256 KB
  float*  dwe      = (float*)(ws + 1572864);              // 1 MB
  float*  dw       = (float*)(ws + 2621440);              // 8 KB
  float*  se       = (float*)(ws + 2629632);              // 8 KB
  float*  smoothed = (float*)(ws + 2637824);              // 8 KB
  double* loss_acc = (double*)(ws + 2646016);             // 8 B
  int*    flagcnt  = (int*)(ws + 2646024);                // 4 B

  hipMemsetAsync(ws + 1572864, 0, 1048576 + 8192, stream);  // dwe + dw
  hipMemsetAsync(ws + 2646016, 0, 12, stream);              // loss_acc + flagcnt

  k_split<<<(KCODE * DDIM) / 256, 256, 0, stream>>>(emb, ehi, elo);
  k_sumsq_emb<<<(KCODE + 255) / 256, 256, 0, stream>>>(emb, se);
  k_screen<<<NROWS / 128, 256, 0, stream>>>(x, ehi, elo, se, out_idx, idx, flaglist, flagcnt);
  k_exact<<<2048, 64, 0, stream>>>(x, emb, se, flaglist, flagcnt, idx, out_idx);
  k_quant<<<(NROWS * 32) / 256, 256, 0, stream>>>(x, emb, idx, out_q, dw, dwe, loss_acc);
  k_final1<<<1, 1024, 0, stream>>>(cs, dw, out_ncs, smoothed, loss_acc, out_loss);
  k_final2<<<(KCODE * DDIM) / 256, 256, 0, stream>>>(ea, dwe, smoothed, out_ne, out_nea);
}